// Round 4
// baseline (580.969 us; speedup 1.0000x reference)
//
#include <hip/hip_runtime.h>
#include <float.h>

// Problem constants
#define NUM_Q 8
#define BN    8192      // B*N tokens
#define D     512
#define C     1024

// d_out layout (floats): [quantized_out | indices(as float) | losses]
#define QOUT_OFF 0
#define IDX_OFF  (BN * D)
#define LOSS_OFF (IDX_OFF + BN * NUM_Q)

// d_ws byte offsets: R_f16 | cb_f16 (all layers) | top2 | e2
#define RF16_B   0
#define CBF16_B  (BN * D * 2)                          // +8 MB
#define TOP2_B   (CBF16_B + NUM_Q * C * D * 2)         // +8 MB
#define E2_B     (TOP2_B + BN * 16 * 8)                // +1 MB

typedef _Float16 f16x8 __attribute__((ext_vector_type(8)));
typedef float    f32x4 __attribute__((ext_vector_type(4)));

// Approx-GEMM tiling: 128 tokens x 128 codewords, BK=64, 8 waves (64x32 tiles)
#define TM 128
#define TN 128
#define BK 64

__device__ __forceinline__ unsigned fkey(float f) {
    unsigned u = __float_as_uint(f);
    return (u & 0x80000000u) ? ~u : (u | 0x80000000u);
}
__device__ __forceinline__ unsigned long long u64min(unsigned long long a, unsigned long long b) {
    return a < b ? a : b;
}
__device__ __forceinline__ unsigned long long u64max(unsigned long long a, unsigned long long b) {
    return a > b ? a : b;
}
__device__ __forceinline__ unsigned long long shfl_xor_u64(unsigned long long v, int m) {
    int lo = __shfl_xor((int)(unsigned)v, m, 64);
    int hi = __shfl_xor((int)(unsigned)(v >> 32), m, 64);
    return ((unsigned long long)(unsigned)hi << 32) | (unsigned)lo;
}
__device__ __forceinline__ void glds16(const void* g, void* l) {
    __builtin_amdgcn_global_load_lds((const __attribute__((address_space(1))) void*)g,
                                     (__attribute__((address_space(3))) void*)l, 16, 0, 0);
}

// ---------------------------------------------------------------------------
// init: R_f32 (d_out) = x; R_f16 (ws) = f16(x); zero losses
// ---------------------------------------------------------------------------
__global__ void rvq_init_kernel(const float* __restrict__ x, float* __restrict__ out,
                                _Float16* __restrict__ Rf) {
    const int i = blockIdx.x * blockDim.x + threadIdx.x;   // 0 .. 524287 (8-elem groups)
    const float* xp = x + (size_t)i * 8;
    float4 a = *(const float4*)xp;
    float4 b = *(const float4*)(xp + 4);
    float* rp = out + QOUT_OFF + (size_t)i * 8;
    *(float4*)rp = a;
    *(float4*)(rp + 4) = b;
    f16x8 h;
    h[0]=(_Float16)a.x; h[1]=(_Float16)a.y; h[2]=(_Float16)a.z; h[3]=(_Float16)a.w;
    h[4]=(_Float16)b.x; h[5]=(_Float16)b.y; h[6]=(_Float16)b.z; h[7]=(_Float16)b.w;
    *(f16x8*)(Rf + (size_t)i * 8) = h;
    if (i < NUM_Q) out[LOSS_OFF + i] = 0.0f;
}

// ---------------------------------------------------------------------------
// prep: cb_f16 = f16(codebooks); e2 = row squared norms. one wave per row.
// ---------------------------------------------------------------------------
__global__ void rvq_prep_kernel(const float* __restrict__ cbs, _Float16* __restrict__ cbf,
                                float* __restrict__ e2ws) {
    const int row = blockIdx.x;          // 0 .. NUM_Q*C-1
    const int lane = threadIdx.x;        // 0..63
    const float* p = cbs + (size_t)row * D + lane * 8;
    float4 a = *(const float4*)p;
    float4 b = *(const float4*)(p + 4);
    f16x8 h;
    h[0]=(_Float16)a.x; h[1]=(_Float16)a.y; h[2]=(_Float16)a.z; h[3]=(_Float16)a.w;
    h[4]=(_Float16)b.x; h[5]=(_Float16)b.y; h[6]=(_Float16)b.z; h[7]=(_Float16)b.w;
    *(f16x8*)(cbf + (size_t)row * D + lane * 8) = h;
    float ss = a.x*a.x + a.y*a.y + a.z*a.z + a.w*a.w
             + b.x*b.x + b.y*b.y + b.z*b.z + b.w*b.w;
#pragma unroll
    for (int off = 32; off >= 1; off >>= 1) ss += __shfl_xor(ss, off, 64);
    if (lane == 0) e2ws[row] = ss;
}

// ---------------------------------------------------------------------------
// approx pass: f16 MFMA GEMM with global_load_lds staging (XOR-swizzled LDS).
// Emits per-token per-block top-2 approx candidates.
// LDS granule = 16 B (8 f16). slot p holds (r = p>>3, g = (p&7) ^ (r&7)).
// ---------------------------------------------------------------------------
__global__ __launch_bounds__(512, 4) void rvq_approx_kernel(
    const _Float16* __restrict__ cbf,    // layer codebook f16 [C][D]
    const _Float16* __restrict__ Rf,     // residual f16 [BN][D]
    const float* __restrict__ e2,        // layer e2 [C]
    unsigned long long* __restrict__ top2)  // [BN][16]
{
    __shared__ __align__(16) char AB[32768];   // A tile 16 KB | B tile 16 KB

    const int tid  = threadIdx.x;
    const int lane = tid & 63;
    const int wv   = tid >> 6;
    const int wm   = wv & 1;     // token half (64)
    const int wn   = wv >> 1;    // codeword slice (32)
    const int lm   = lane & 15;
    const int lq   = lane >> 4;
    const int m7   = lm & 7;

    const int mg = blockIdx.x & 63;
    const int nb = blockIdx.x >> 6;
    const int tok0 = mg * TM;
    const int cb0  = nb * TN;

    // staging: wave wv owns issues q = wv*4 + j. q<16 -> A, else B.
    const _Float16* gbase[4];
    char* lbase[4];
#pragma unroll
    for (int j = 0; j < 4; ++j) {
        const int q = wv * 4 + j;
        const int ps = (q & 15) * 64 + lane;     // granule slot within tile
        const int r  = ps >> 3;
        const int g  = (ps & 7) ^ (r & 7);
        gbase[j] = (q < 16) ? (Rf  + (size_t)(tok0 + r) * D + g * 8)
                            : (cbf + (size_t)(cb0  + r) * D + g * 8);
        lbase[j] = AB + q * 1024;
    }

    f32x4 acc[4][2];
#pragma unroll
    for (int mt = 0; mt < 4; ++mt)
#pragma unroll
        for (int nt = 0; nt < 2; ++nt)
            acc[mt][nt] = (f32x4){0.f, 0.f, 0.f, 0.f};

    for (int kb = 0; kb < D / BK; ++kb) {
        const int kc = kb * BK;
        __syncthreads();                         // prior frag reads done
#pragma unroll
        for (int j = 0; j < 4; ++j)
            glds16(gbase[j] + kc, lbase[j]);
        __syncthreads();                         // loads drained (vmcnt0 at barrier)

#pragma unroll
        for (int kh = 0; kh < 2; ++kh) {
            f16x8 ah[4], bh[2];
            const int x = ((kh * 4 + lq) ^ m7) * 16;
#pragma unroll
            for (int mt = 0; mt < 4; ++mt) {
                const int rr = wm * 64 + mt * 16 + lm;
                ah[mt] = *(const f16x8*)(AB + rr * 128 + x);
            }
#pragma unroll
            for (int nt = 0; nt < 2; ++nt) {
                const int rr = wn * 32 + nt * 16 + lm;
                bh[nt] = *(const f16x8*)(AB + 16384 + rr * 128 + x);
            }
#pragma unroll
            for (int mt = 0; mt < 4; ++mt)
#pragma unroll
                for (int nt = 0; nt < 2; ++nt)
                    acc[mt][nt] = __builtin_amdgcn_mfma_f32_16x16x32_f16(ah[mt], bh[nt], acc[mt][nt], 0, 0, 0);
        }
    }

    __syncthreads();   // reuse AB as the cross-wave top-2 scratch
    unsigned long long (*part)[TM][2] = (unsigned long long (*)[TM][2])AB;

    const int n0 = cb0 + wn * 32 + lm;
    const float e2v0 = e2[n0];
    const float e2v1 = e2[n0 + 16];

#pragma unroll
    for (int mt = 0; mt < 4; ++mt) {
#pragma unroll
        for (int r = 0; r < 4; ++r) {
            float s0 = e2v0 - 2.0f * acc[mt][0][r];
            float s1 = e2v1 - 2.0f * acc[mt][1][r];
            unsigned long long pa = ((unsigned long long)fkey(s0) << 32) | (unsigned)n0;
            unsigned long long pb = ((unsigned long long)fkey(s1) << 32) | (unsigned)(n0 + 16);
            unsigned long long lo = u64min(pa, pb);
            unsigned long long hi = u64max(pa, pb);
#pragma unroll
            for (int m = 1; m < 16; m <<= 1) {
                unsigned long long o1 = shfl_xor_u64(lo, m);
                unsigned long long o2 = shfl_xor_u64(hi, m);
                unsigned long long n1 = u64min(lo, o1);
                unsigned long long n2 = u64min(u64max(lo, o1), u64min(hi, o2));
                lo = n1; hi = n2;
            }
            if (lm == 0) {
                const int trow = wm * 64 + mt * 16 + lq * 4 + r;
                part[wn][trow][0] = lo;
                part[wn][trow][1] = hi;
            }
        }
    }
    __syncthreads();
    if (tid < TM) {
        unsigned long long lo = part[0][tid][0];
        unsigned long long hi = part[0][tid][1];
#pragma unroll
        for (int w = 1; w < 4; ++w) {
            unsigned long long q1 = part[w][tid][0];
            unsigned long long q2 = part[w][tid][1];
            unsigned long long n1 = u64min(lo, q1);
            unsigned long long n2 = u64min(u64max(lo, q1), u64min(hi, q2));
            lo = n1; hi = n2;
        }
        unsigned long long* dst = top2 + (size_t)(tok0 + tid) * 16 + nb * 2;
        dst[0] = lo;
        dst[1] = hi;
    }
}

// ---------------------------------------------------------------------------
// rescore + update: exact fp32 score for 16 candidates, parallel across lanes
// (lane = cand(16) x k-range(4)); pick min (index tie-break); residual -=
// codeword (f32 + f16 mirrors); loss partial; emit index.
// one wave per token, 8 tokens per block.
// ---------------------------------------------------------------------------
__global__ __launch_bounds__(512) void rvq_rescore_update_kernel(
    const float* __restrict__ cb, const float* __restrict__ e2,
    const unsigned long long* __restrict__ top2,
    float* __restrict__ out, _Float16* __restrict__ Rf, int q)
{
    __shared__ float rsh[8][512];
    __shared__ float lsum[8];
    const int tid  = threadIdx.x;
    const int lane = tid & 63;
    const int w    = tid >> 6;
    const int tok  = blockIdx.x * 8 + w;

    float* rrow = out + QOUT_OFF + (size_t)tok * D;
    float4 r0 = *(const float4*)(rrow + lane * 8);
    float4 r1 = *(const float4*)(rrow + lane * 8 + 4);
    *(float4*)&rsh[w][lane * 8]     = r0;
    *(float4*)&rsh[w][lane * 8 + 4] = r1;
    __syncthreads();

    const int c = lane & 15;             // candidate id
    const int g = lane >> 4;             // k-range id
    const unsigned long long pk = top2[(size_t)tok * 16 + c];
    const int idx = (int)(unsigned)(pk & 0xFFFFFFFFull);

    const float* crow = cb + (size_t)idx * D + g * 128;
    const float* rp   = &rsh[w][g * 128];
    float dot = 0.0f;
#pragma unroll 8
    for (int i = 0; i < 32; ++i) {
        float4 cv = *(const float4*)(crow + i * 4);
        float4 rv = *(const float4*)(rp + i * 4);
        dot += cv.x*rv.x + cv.y*rv.y + cv.z*rv.z + cv.w*rv.w;
    }
    dot += __shfl_xor(dot, 16, 64);
    dot += __shfl_xor(dot, 32, 64);      // all 4 replicas now hold full dot

    const float s = e2[idx] - 2.0f * dot;
    unsigned long long key = ((unsigned long long)fkey(s) << 32) | (unsigned)idx;
#pragma unroll
    for (int m = 1; m < 64; m <<= 1) key = u64min(key, shfl_xor_u64(key, m));
    const int bi = (int)(unsigned)(key & 0xFFFFFFFFull);

    const float* brow = cb + (size_t)bi * D + lane * 8;
    float4 c0 = *(const float4*)brow;
    float4 c1 = *(const float4*)(brow + 4);
    float4 n0 = make_float4(r0.x - c0.x, r0.y - c0.y, r0.z - c0.z, r0.w - c0.w);
    float4 n1 = make_float4(r1.x - c1.x, r1.y - c1.y, r1.z - c1.z, r1.w - c1.w);
    *(float4*)(rrow + lane * 8)     = n0;
    *(float4*)(rrow + lane * 8 + 4) = n1;
    f16x8 h;
    h[0]=(_Float16)n0.x; h[1]=(_Float16)n0.y; h[2]=(_Float16)n0.z; h[3]=(_Float16)n0.w;
    h[4]=(_Float16)n1.x; h[5]=(_Float16)n1.y; h[6]=(_Float16)n1.z; h[7]=(_Float16)n1.w;
    *(f16x8*)(Rf + (size_t)tok * D + lane * 8) = h;

    float ss = n0.x*n0.x + n0.y*n0.y + n0.z*n0.z + n0.w*n0.w
             + n1.x*n1.x + n1.y*n1.y + n1.z*n1.z + n1.w*n1.w;
#pragma unroll
    for (int off = 32; off >= 1; off >>= 1) ss += __shfl_xor(ss, off, 64);
    if (lane == 0) {
        out[IDX_OFF + (size_t)tok * NUM_Q + q] = (float)bi;
        lsum[w] = ss;
    }
    __syncthreads();
    if (tid == 0) {
        float tot = 0.0f;
#pragma unroll
        for (int i = 0; i < 8; ++i) tot += lsum[i];
        atomicAdd(out + LOSS_OFF + q, tot);
    }
}

// ---------------------------------------------------------------------------
// finalize: quantized_out = x - residual_final (in place); scale losses
// ---------------------------------------------------------------------------
__global__ void rvq_finalize_kernel(const float* __restrict__ x, float* __restrict__ out) {
    int i = blockIdx.x * blockDim.x + threadIdx.x;
    const float4* x4 = (const float4*)x;
    float4* o4 = (float4*)(out + QOUT_OFF);
    const int n4 = BN * D / 4;
    for (int k = i; k < n4; k += gridDim.x * blockDim.x) {
        float4 xv = x4[k];
        float4 rv = o4[k];
        o4[k] = make_float4(xv.x - rv.x, xv.y - rv.y, xv.z - rv.z, xv.w - rv.w);
    }
    if (i < NUM_Q) out[LOSS_OFF + i] *= (1.0f / (float)(BN * D));
}

extern "C" void kernel_launch(void* const* d_in, const int* in_sizes, int n_in,
                              void* d_out, int out_size, void* d_ws, size_t ws_size,
                              hipStream_t stream) {
    const float* x   = (const float*)d_in[0];
    const float* cbs = (const float*)d_in[1];
    float* out = (float*)d_out;
    char* ws = (char*)d_ws;
    _Float16* Rf   = (_Float16*)(ws + RF16_B);
    _Float16* cbf  = (_Float16*)(ws + CBF16_B);
    unsigned long long* top2 = (unsigned long long*)(ws + TOP2_B);
    float* e2ws = (float*)(ws + E2_B);

    hipLaunchKernelGGL(rvq_init_kernel, dim3(BN * D / 8 / 256), dim3(256), 0, stream, x, out, Rf);
    hipLaunchKernelGGL(rvq_prep_kernel, dim3(NUM_Q * C), dim3(64), 0, stream, cbs, cbf, e2ws);

    for (int q = 0; q < NUM_Q; ++q) {
        hipLaunchKernelGGL(rvq_approx_kernel, dim3((BN / TM) * (C / TN)), dim3(512), 0, stream,
                           cbf + (size_t)q * C * D, Rf, e2ws + (size_t)q * C, top2);
        hipLaunchKernelGGL(rvq_rescore_update_kernel, dim3(BN / 8), dim3(512), 0, stream,
                           cbs + (size_t)q * C * D, e2ws + (size_t)q * C, top2, out, Rf, q);
    }
    hipLaunchKernelGGL(rvq_finalize_kernel, dim3(1024), dim3(256), 0, stream, x, out);
}